// Round 1
// baseline (1220.656 us; speedup 1.0000x reference)
//
#include <hip/hip_runtime.h>
#include <math.h>
#include <stdint.h>

#define NPOL 125
#define NANG 126
#define BB 32
#define CC 64
#define HH 128
#define WW 128
#define PIX (NPOL*NPOL)          // 15625
#define PI_F 3.14159265358979323846f

// ---------------------------------------------------------------------------
// K0: per-pixel bilinear metadata for the polar grid (shared by all b,c).
// pk packs the 4 clipped corner indices; w?? are weights pre-multiplied by
// the per-corner validity mask (zero padding semantics).
// ---------------------------------------------------------------------------
__global__ __launch_bounds__(256) void k0_meta(int* __restrict__ pk,
                                               float* __restrict__ w00, float* __restrict__ w01,
                                               float* __restrict__ w10, float* __restrict__ w11) {
    int idx = blockIdx.x * 256 + threadIdx.x;
    if (idx >= PIX) return;
    int i = idx / NPOL;          // v (angle) index
    int j = idx - i * NPOL;      // u (radius) index
    float u = (float)j * (1.4142135623730951f / 124.0f);
    float v = -PI_F + (float)i * (2.0f * PI_F / 124.0f);
    float x = u * cosf(v);
    float y = u * sinf(v);
    float ix = (x + 1.0f) * 0.5f * (float)(WW - 1);
    float iy = (y + 1.0f) * 0.5f * (float)(HH - 1);
    float x0 = floorf(ix), y0 = floorf(iy);
    float x1 = x0 + 1.0f,  y1 = y0 + 1.0f;
    float wx0 = x1 - ix, wx1 = ix - x0;
    float wy0 = y1 - iy, wy1 = iy - y0;
    bool vx0 = (x0 >= 0.0f) && (x0 <= 127.0f);
    bool vx1 = (x1 >= 0.0f) && (x1 <= 127.0f);
    bool vy0 = (y0 >= 0.0f) && (y0 <= 127.0f);
    bool vy1 = (y1 >= 0.0f) && (y1 <= 127.0f);
    int xi0 = (int)fminf(fmaxf(x0, 0.0f), 127.0f);
    int xi1 = (int)fminf(fmaxf(x1, 0.0f), 127.0f);
    int yi0 = (int)fminf(fmaxf(y0, 0.0f), 127.0f);
    int yi1 = (int)fminf(fmaxf(y1, 0.0f), 127.0f);
    pk[idx]  = xi0 | (yi0 << 8) | (xi1 << 16) | (yi1 << 24);
    w00[idx] = wx0 * wy0 * (float)(vx0 && vy0);
    w01[idx] = wx1 * wy0 * (float)(vx1 && vy0);
    w10[idx] = wx0 * wy1 * (float)(vx0 && vy1);
    w11[idx] = wx1 * wy1 * (float)(vx1 && vy1);
}

// ---------------------------------------------------------------------------
// K1: polar grid_sample. One thread per output element, j fastest (coalesced).
// ---------------------------------------------------------------------------
__global__ __launch_bounds__(256) void k1_sample(const float* __restrict__ img, float* __restrict__ out,
                                                 const int* __restrict__ pk,
                                                 const float* __restrict__ w00, const float* __restrict__ w01,
                                                 const float* __restrict__ w10, const float* __restrict__ w11) {
    int n = blockIdx.x * 256 + threadIdx.x;
    if (n >= BB * CC * PIX) return;
    int pix = n % PIX;
    int bc  = n / PIX;
    const float* plane = img + (size_t)bc * (HH * WW);
    int p = pk[pix];
    int xi0 = p & 255, yi0 = (p >> 8) & 255, xi1 = (p >> 16) & 255, yi1 = (p >> 24) & 255;
    float val = w00[pix] * plane[yi0 * WW + xi0]
              + w01[pix] * plane[yi0 * WW + xi1]
              + w10[pix] * plane[yi1 * WW + xi0]
              + w11[pix] * plane[yi1 * WW + xi1];
    out[n] = val;
}

// ---------------------------------------------------------------------------
// K2: grouped correlation, one block per (b,c).
// partial[b,c,t] = sum_{i,j} aug[b,c,t+i,j] * P2[b,c,i,j],
// aug[b,c,y,:] = P1[b,c,y,:] for y<125 else P1[31-b,63-c,y-125,:].
// Full aug plane (252x128 f32, rows 250/251 zero, cols 125..127 zero) in LDS;
// P2 streamed in 5 tiles of 25 rows. Each thread owns 8 consecutive t's
// (sliding register window over aug rows) x one float4 column slot.
// LDS-throughput bound: 2 ds_read_b128 per 32 MACs per lane.
// ---------------------------------------------------------------------------
#define FMA4(A, W, P) \
    A.x = fmaf(W.x, P.x, A.x); A.y = fmaf(W.y, P.y, A.y); \
    A.z = fmaf(W.z, P.z, A.z); A.w = fmaf(W.w, P.w, A.w);

__global__ __launch_bounds__(256) void k2_corr(const float* __restrict__ P1, const float* __restrict__ P2,
                                               float* __restrict__ partial) {
    __shared__ float augs[252][128];   // 129024 B
    __shared__ float p2s[25][128];     //  12800 B
    const int b   = blockIdx.x >> 6;
    const int c   = blockIdx.x & 63;
    const int tid = threadIdx.x;

    const size_t plA = ((size_t)(b * CC + c)) * PIX;                     // P1[b,c]
    const size_t plB = ((size_t)((BB - 1 - b) * CC + (CC - 1 - c))) * PIX; // flipped
    const size_t plK = ((size_t)(b * CC + c)) * PIX;                     // P2[b,c]

    // Stage the full aug plane once.
    {
        const int j = tid & 127;
        for (int r = tid >> 7; r < 252; r += 2) {
            float v = 0.0f;
            if (r < 250 && j < 125)
                v = (r < 125) ? P1[plA + r * NPOL + j] : P1[plB + (r - 125) * NPOL + j];
            augs[r][j] = v;
        }
    }
    __syncthreads();

    float4 acc[2][8];
    #pragma unroll
    for (int a = 0; a < 2; ++a)
        #pragma unroll
        for (int k = 0; k < 8; ++k) acc[a][k] = make_float4(0.f, 0.f, 0.f, 0.f);

    const int j4 = tid & 31;   // float4 column slot (covers j = 4*j4..4*j4+3)
    const int tg = tid >> 5;   // 0..7

    for (int it = 0; it < 5; ++it) {
        const int i0 = it * 25;
        for (int idx = tid; idx < 25 * 128; idx += 256) {
            int r = idx >> 7, j = idx & 127;
            p2s[r][j] = (j < 125) ? P2[plK + (i0 + r) * NPOL + j] : 0.0f;
        }
        __syncthreads();

        const float4* augF = (const float4*)&augs[0][0];
        const float4* p2F  = (const float4*)&p2s[0][0];
        #pragma unroll
        for (int pt = 0; pt < 2; ++pt) {
            const int t0 = (tg + 8 * pt) * 8;   // 0,8,...,120
            const int rb = t0 + i0;
            float4 v0 = augF[(rb + 0) * 32 + j4];
            float4 v1 = augF[(rb + 1) * 32 + j4];
            float4 v2 = augF[(rb + 2) * 32 + j4];
            float4 v3 = augF[(rb + 3) * 32 + j4];
            float4 v4 = augF[(rb + 4) * 32 + j4];
            float4 v5 = augF[(rb + 5) * 32 + j4];
            float4 v6 = augF[(rb + 6) * 32 + j4];
            float4 v7 = augF[(rb + 7) * 32 + j4];
            #pragma unroll
            for (int ii = 0; ii < 25; ++ii) {
                float4 pv = p2F[ii * 32 + j4];
                FMA4(acc[pt][0], v0, pv); FMA4(acc[pt][1], v1, pv);
                FMA4(acc[pt][2], v2, pv); FMA4(acc[pt][3], v3, pv);
                FMA4(acc[pt][4], v4, pv); FMA4(acc[pt][5], v5, pv);
                FMA4(acc[pt][6], v6, pv); FMA4(acc[pt][7], v7, pv);
                if (ii < 24) {
                    v0 = v1; v1 = v2; v2 = v3; v3 = v4; v4 = v5; v5 = v6; v6 = v7;
                    v7 = augF[(rb + 8 + ii) * 32 + j4];
                }
            }
        }
        __syncthreads();
    }

    // Reduce the 4 j-components then the 32 column slots per t; lane j4==0 writes.
    #pragma unroll
    for (int pt = 0; pt < 2; ++pt) {
        const int t0 = (tg + 8 * pt) * 8;
        #pragma unroll
        for (int k = 0; k < 8; ++k) {
            float s = acc[pt][k].x + acc[pt][k].y + acc[pt][k].z + acc[pt][k].w;
            s += __shfl_xor(s, 16);
            s += __shfl_xor(s, 8);
            s += __shfl_xor(s, 4);
            s += __shfl_xor(s, 2);
            s += __shfl_xor(s, 1);
            if (j4 == 0) {
                int t = t0 + k;
                if (t < NANG) partial[(size_t)(b * CC + c) * NANG + t] = s;
            }
        }
    }
}

// ---------------------------------------------------------------------------
// K3: reduce partials over c, softmax over t, theta -> Mat. One block per b.
// ---------------------------------------------------------------------------
__global__ __launch_bounds__(128) void k3_theta(const float* __restrict__ partial, float* __restrict__ matOut) {
    const int b = blockIdx.x;
    const int t = threadIdx.x;   // 0..127
    __shared__ float sd[128];
    __shared__ float red[128];

    float sval = -1e30f;
    if (t < NANG) {
        float acc = 0.0f;
        const float* p = partial + (size_t)b * CC * NANG + t;
        for (int c = 0; c < CC; ++c) acc += p[c * NANG];
        sval = acc;
    }
    sd[t]  = sval;
    red[t] = sval;
    __syncthreads();
    for (int st = 64; st > 0; st >>= 1) {
        if (t < st) red[t] = fmaxf(red[t], red[t + st]);
        __syncthreads();
    }
    const float m = red[0];
    __syncthreads();
    const float e = (t < NANG) ? expf(sd[t] - m) : 0.0f;
    red[t] = e;
    __syncthreads();
    for (int st = 64; st > 0; st >>= 1) {
        if (t < st) red[t] += red[t + st];
        __syncthreads();
    }
    const float Z = red[0];
    __syncthreads();
    const float ang = -PI_F + (float)t * (2.0f * PI_F / 125.0f);
    red[t] = e * ang;
    __syncthreads();
    for (int st = 64; st > 0; st >>= 1) {
        if (t < st) red[t] += red[t + st];
        __syncthreads();
    }
    if (t == 0) {
        float theta = red[0] / Z - PI_F;
        float cth = cosf(theta), sth = sinf(theta);
        float* M = matOut + b * 6;
        M[0] = cth; M[1] = -sth; M[2] = 0.0f;
        M[3] = sth; M[4] = cth;  M[5] = 0.0f;
    }
}

// ---------------------------------------------------------------------------
// K4: affine grid + grid_sample of Embd1 with Mat. One thread per output.
// ---------------------------------------------------------------------------
__global__ __launch_bounds__(256) void k4_affine(const float* __restrict__ img, const float* __restrict__ mat,
                                                 float* __restrict__ out) {
    int n = blockIdx.x * 256 + threadIdx.x;
    if (n >= BB * CC * PIX) return;
    int pix = n % PIX;
    int bc  = n / PIX;
    int b   = bc >> 6;
    int i = pix / NPOL;
    int j = pix - i * NPOL;
    float xx = -1.0f + (float)j * (2.0f / 124.0f);
    float yy = -1.0f + (float)i * (2.0f / 124.0f);
    const float* M = mat + b * 6;
    float gx = M[0] * xx + M[1] * yy + M[2];
    float gy = M[3] * xx + M[4] * yy + M[5];
    float ix = (gx + 1.0f) * 0.5f * (float)(WW - 1);
    float iy = (gy + 1.0f) * 0.5f * (float)(HH - 1);
    float x0 = floorf(ix), y0 = floorf(iy);
    float x1 = x0 + 1.0f,  y1 = y0 + 1.0f;
    float wx0 = x1 - ix, wx1 = ix - x0;
    float wy0 = y1 - iy, wy1 = iy - y0;
    bool vx0 = (x0 >= 0.0f) && (x0 <= 127.0f);
    bool vx1 = (x1 >= 0.0f) && (x1 <= 127.0f);
    bool vy0 = (y0 >= 0.0f) && (y0 <= 127.0f);
    bool vy1 = (y1 >= 0.0f) && (y1 <= 127.0f);
    int xi0 = (int)fminf(fmaxf(x0, 0.0f), 127.0f);
    int xi1 = (int)fminf(fmaxf(x1, 0.0f), 127.0f);
    int yi0 = (int)fminf(fmaxf(y0, 0.0f), 127.0f);
    int yi1 = (int)fminf(fmaxf(y1, 0.0f), 127.0f);
    const float* plane = img + (size_t)bc * (HH * WW);
    float val = (wx0 * wy0 * (float)(vx0 && vy0)) * plane[yi0 * WW + xi0]
              + (wx1 * wy0 * (float)(vx1 && vy0)) * plane[yi0 * WW + xi1]
              + (wx0 * wy1 * (float)(vx0 && vy1)) * plane[yi1 * WW + xi0]
              + (wx1 * wy1 * (float)(vx1 && vy1)) * plane[yi1 * WW + xi1];
    out[n] = val;
}

// ---------------------------------------------------------------------------
// Launch: P1 lives in d_out[0..32M) (dead before k4 overwrites it).
// ws layout: P2 (128,000,000 B) | partial (1,032,192 B) | meta (312,500 B)
// total ~129.35 MB required.
// ---------------------------------------------------------------------------
extern "C" void kernel_launch(void* const* d_in, const int* in_sizes, int n_in,
                              void* d_out, int out_size, void* d_ws, size_t ws_size,
                              hipStream_t stream) {
    const float* E1 = (const float*)d_in[0];
    const float* E2 = (const float*)d_in[1];
    float* out    = (float*)d_out;
    float* P1     = out;                       // 32,000,000 floats
    float* matOut = out + 32000000;            // 192 floats (Mat output)

    char*  ws      = (char*)d_ws;
    float* P2      = (float*)ws;                            // 128,000,000 B
    float* partial = (float*)(ws + 128000000);              // 1,032,192 B
    char*  meta    = ws + 128000000 + 1032192;
    int*   pk  = (int*)meta;
    float* w00 = (float*)(meta + 1 * 62500);
    float* w01 = (float*)(meta + 2 * 62500);
    float* w10 = (float*)(meta + 3 * 62500);
    float* w11 = (float*)(meta + 4 * 62500);

    k0_meta<<<(PIX + 255) / 256, 256, 0, stream>>>(pk, w00, w01, w10, w11);

    const int nElem  = BB * CC * PIX;          // 32,000,000
    const int nBlk   = nElem / 256;            // 125,000 (exact)
    k1_sample<<<nBlk, 256, 0, stream>>>(E1, P1, pk, w00, w01, w10, w11);
    k1_sample<<<nBlk, 256, 0, stream>>>(E2, P2, pk, w00, w01, w10, w11);

    k2_corr<<<BB * CC, 256, 0, stream>>>(P1, P2, partial);
    k3_theta<<<BB, 128, 0, stream>>>(partial, matOut);
    k4_affine<<<nBlk, 256, 0, stream>>>(E1, matOut, out);
}

// Round 2
// 885.566 us; speedup vs baseline: 1.3784x; 1.3784x over previous
//
#include <hip/hip_runtime.h>
#include <math.h>
#include <stdint.h>

#define NPOL 125
#define NANG 126
#define BB 32
#define CC 64
#define HH 128
#define WW 128
#define PIX (NPOL*NPOL)          // 15625
#define PI_F 3.14159265358979323846f

typedef __attribute__((ext_vector_type(8))) short bf16x8;
typedef __attribute__((ext_vector_type(4))) float f32x4;

// bf16 split helpers: v = hi + lo, each bf16 (RNE). Packed as (lo<<16)|hi in u32.
__device__ __forceinline__ unsigned f2bf(float f) {
    union { float f; unsigned u; } x; x.f = f;
    return (x.u + 0x7fffu + ((x.u >> 16) & 1u)) >> 16;
}
__device__ __forceinline__ float bf2f(unsigned h) {
    union { float f; unsigned u; } x; x.u = h << 16;
    return x.f;
}

// ---------------------------------------------------------------------------
// K0: per-pixel bilinear metadata for the polar grid (shared by all b,c).
// ---------------------------------------------------------------------------
__global__ __launch_bounds__(256) void k0_meta(int* __restrict__ pk,
                                               float* __restrict__ w00, float* __restrict__ w01,
                                               float* __restrict__ w10, float* __restrict__ w11) {
    int idx = blockIdx.x * 256 + threadIdx.x;
    if (idx >= PIX) return;
    int i = idx / NPOL;
    int j = idx - i * NPOL;
    float u = (float)j * (1.4142135623730951f / 124.0f);
    float v = -PI_F + (float)i * (2.0f * PI_F / 124.0f);
    float x = u * cosf(v);
    float y = u * sinf(v);
    float ix = (x + 1.0f) * 0.5f * (float)(WW - 1);
    float iy = (y + 1.0f) * 0.5f * (float)(HH - 1);
    float x0 = floorf(ix), y0 = floorf(iy);
    float x1 = x0 + 1.0f,  y1 = y0 + 1.0f;
    float wx0 = x1 - ix, wx1 = ix - x0;
    float wy0 = y1 - iy, wy1 = iy - y0;
    bool vx0 = (x0 >= 0.0f) && (x0 <= 127.0f);
    bool vx1 = (x1 >= 0.0f) && (x1 <= 127.0f);
    bool vy0 = (y0 >= 0.0f) && (y0 <= 127.0f);
    bool vy1 = (y1 >= 0.0f) && (y1 <= 127.0f);
    int xi0 = (int)fminf(fmaxf(x0, 0.0f), 127.0f);
    int xi1 = (int)fminf(fmaxf(x1, 0.0f), 127.0f);
    int yi0 = (int)fminf(fmaxf(y0, 0.0f), 127.0f);
    int yi1 = (int)fminf(fmaxf(y1, 0.0f), 127.0f);
    pk[idx]  = xi0 | (yi0 << 8) | (xi1 << 16) | (yi1 << 24);
    w00[idx] = wx0 * wy0 * (float)(vx0 && vy0);
    w01[idx] = wx1 * wy0 * (float)(vx1 && vy0);
    w10[idx] = wx0 * wy1 * (float)(vx0 && vy1);
    w11[idx] = wx1 * wy1 * (float)(vx1 && vy1);
}

// ---------------------------------------------------------------------------
// K1: polar grid_sample -> split-bf16 packed u32 ((lo<<16)|hi).
// ---------------------------------------------------------------------------
__global__ __launch_bounds__(256) void k1_sample_pk(const float* __restrict__ img, unsigned* __restrict__ out,
                                                    const int* __restrict__ pk,
                                                    const float* __restrict__ w00, const float* __restrict__ w01,
                                                    const float* __restrict__ w10, const float* __restrict__ w11) {
    int n = blockIdx.x * 256 + threadIdx.x;
    if (n >= BB * CC * PIX) return;
    int pix = n % PIX;
    int bc  = n / PIX;
    const float* plane = img + (size_t)bc * (HH * WW);
    int p = pk[pix];
    int xi0 = p & 255, yi0 = (p >> 8) & 255, xi1 = (p >> 16) & 255, yi1 = (p >> 24) & 255;
    float val = w00[pix] * plane[yi0 * WW + xi0]
              + w01[pix] * plane[yi0 * WW + xi1]
              + w10[pix] * plane[yi1 * WW + xi0]
              + w11[pix] * plane[yi1 * WW + xi1];
    unsigned hb = f2bf(val);
    unsigned lb = f2bf(val - bf2f(hb));
    out[n] = (lb << 16) | hb;
}

// ---------------------------------------------------------------------------
// KZ: zero the scores accumulator.
// ---------------------------------------------------------------------------
__global__ __launch_bounds__(256) void kz_zero(float* __restrict__ p, int n) {
    int i = blockIdx.x * 256 + threadIdx.x;
    if (i < n) p[i] = 0.0f;
}

// ---------------------------------------------------------------------------
// K2: correlation as GEMM + diagonal-band reduction.
// Per b: R = G * Q^T, G[r, (c,j)] = aug rows (250x8192 split-bf16),
//        Q[i, (c,j)] = P2 rows (125x8192). scores[b,t] = sum_i R[t+i, i].
// Grid: 32 b x 8 K-chunks (8 channels each). Block: 512 thr = 8 waves (4Mx2N),
// wave tile 64x64, BK=64, 16x16x32 bf16 MFMA, 3-pass hi/lo split.
// ---------------------------------------------------------------------------
#define LSTR 68   // u32 LDS row stride: 68*4B=272B -> bank rotation 4/row, <=2-way

__device__ __forceinline__ void extract_pair(const unsigned* __restrict__ p, bf16x8& h, bf16x8& l) {
    // p -> 8 packed u32 (16B-aligned); hi bf16 in low half, lo bf16 in high half.
    #pragma unroll
    for (int e = 0; e < 8; ++e) {
        unsigned w = p[e];
        h[e] = (short)(w & 0xffffu);
        l[e] = (short)(w >> 16);
    }
}

__global__ __launch_bounds__(512, 2) void k2_gemm(const unsigned* __restrict__ P1, const unsigned* __restrict__ P2,
                                                  float* __restrict__ scores) {
    __shared__ unsigned As[256][LSTR];   // 69,632 B
    __shared__ unsigned Bs[128][LSTR];   // 34,816 B
    const int b    = blockIdx.x >> 3;
    const int kc   = blockIdx.x & 7;
    const int tid  = threadIdx.x;
    const int lane = tid & 63;
    const int wid  = tid >> 6;
    const int wm   = wid >> 1;           // 0..3
    const int wn   = wid & 1;            // 0..1
    const int kl   = tid & 63;           // staging column
    const int rgrp = tid >> 6;           // staging row group

    f32x4 acc[4][4];
    #pragma unroll
    for (int mi = 0; mi < 4; ++mi)
        #pragma unroll
        for (int ni = 0; ni < 4; ++ni) acc[mi][ni] = (f32x4){0.f, 0.f, 0.f, 0.f};

    const int frow = lane & 15;
    const int fk8  = (lane >> 4) * 8;

    for (int step = 0; step < 16; ++step) {
        const int c_loc = step >> 1;                   // uniform per step
        const int j     = ((step & 1) << 6) + kl;      // 0..127
        const int c     = kc * 8 + c_loc;
        const bool vj   = (j < NPOL);
        const size_t pA0 = (size_t)(b * CC + c) * PIX;                         // rows 0..124
        const size_t pA1 = (size_t)((BB - 1 - b) * CC + (CC - 1 - c)) * PIX;   // rows 125..249

        // Stage A: 256 rows x 64 k (wave-uniform row per iteration, coalesced j).
        #pragma unroll
        for (int s = 0; s < 32; ++s) {
            int r = rgrp * 32 + s;
            unsigned v = 0u;
            if (vj) {
                if (r < NPOL)       v = P1[pA0 + r * NPOL + j];
                else if (r < 250)   v = P1[pA1 + (r - NPOL) * NPOL + j];
            }
            As[r][kl] = v;
        }
        // Stage B: 128 rows x 64 k.
        #pragma unroll
        for (int s = 0; s < 16; ++s) {
            int i = rgrp * 16 + s;
            unsigned v = (vj && i < NPOL) ? P2[pA0 + i * NPOL + j] : 0u;
            Bs[i][kl] = v;
        }
        __syncthreads();

        #pragma unroll
        for (int ki = 0; ki < 2; ++ki) {
            const int col0 = ki * 32 + fk8;
            bf16x8 ah[4], al[4];
            #pragma unroll
            for (int mi = 0; mi < 4; ++mi)
                extract_pair(&As[wm * 64 + mi * 16 + frow][col0], ah[mi], al[mi]);
            #pragma unroll
            for (int ni = 0; ni < 4; ++ni) {
                bf16x8 bh, bl;
                extract_pair(&Bs[wn * 64 + ni * 16 + frow][col0], bh, bl);
                #pragma unroll
                for (int mi = 0; mi < 4; ++mi) {
                    acc[mi][ni] = __builtin_amdgcn_mfma_f32_16x16x32_bf16(ah[mi], bh, acc[mi][ni], 0, 0, 0);
                    acc[mi][ni] = __builtin_amdgcn_mfma_f32_16x16x32_bf16(ah[mi], bl, acc[mi][ni], 0, 0, 0);
                    acc[mi][ni] = __builtin_amdgcn_mfma_f32_16x16x32_bf16(al[mi], bh, acc[mi][ni], 0, 0, 0);
                }
            }
        }
        __syncthreads();
    }

    // Diagonal-band reduction: scores[b,t] += sum over acc elems with t = r - i.
    float* sd = (float*)&As[0][0];
    if (tid < 128) sd[tid] = 0.0f;
    __syncthreads();
    const int rbase = wm * 64 + (lane >> 4) * 4;
    const int ibase = wn * 64 + (lane & 15);
    #pragma unroll
    for (int mi = 0; mi < 4; ++mi) {
        #pragma unroll
        for (int ni = 0; ni < 4; ++ni) {
            const int i = ibase + ni * 16;
            #pragma unroll
            for (int reg = 0; reg < 4; ++reg) {
                const int r = rbase + mi * 16 + reg;
                const int t = r - i;
                if (r < 250 && i < NPOL && t >= 0 && t < NANG)
                    atomicAdd(&sd[t], acc[mi][ni][reg]);
            }
        }
    }
    __syncthreads();
    if (tid < NANG) atomicAdd(&scores[b * NANG + tid], sd[tid]);
}

// ---------------------------------------------------------------------------
// K3: softmax over t, theta -> Mat. One block per b.
// ---------------------------------------------------------------------------
__global__ __launch_bounds__(128) void k3_theta(const float* __restrict__ scores, float* __restrict__ matOut) {
    const int b = blockIdx.x;
    const int t = threadIdx.x;   // 0..127
    __shared__ float sd[128];
    __shared__ float red[128];

    float sval = (t < NANG) ? scores[b * NANG + t] : -1e30f;
    sd[t]  = sval;
    red[t] = sval;
    __syncthreads();
    for (int st = 64; st > 0; st >>= 1) {
        if (t < st) red[t] = fmaxf(red[t], red[t + st]);
        __syncthreads();
    }
    const float m = red[0];
    __syncthreads();
    const float e = (t < NANG) ? expf(sd[t] - m) : 0.0f;
    red[t] = e;
    __syncthreads();
    for (int st = 64; st > 0; st >>= 1) {
        if (t < st) red[t] += red[t + st];
        __syncthreads();
    }
    const float Z = red[0];
    __syncthreads();
    const float ang = -PI_F + (float)t * (2.0f * PI_F / 125.0f);
    red[t] = e * ang;
    __syncthreads();
    for (int st = 64; st > 0; st >>= 1) {
        if (t < st) red[t] += red[t + st];
        __syncthreads();
    }
    if (t == 0) {
        float theta = red[0] / Z - PI_F;
        float cth = cosf(theta), sth = sinf(theta);
        float* M = matOut + b * 6;
        M[0] = cth; M[1] = -sth; M[2] = 0.0f;
        M[3] = sth; M[4] = cth;  M[5] = 0.0f;
    }
}

// ---------------------------------------------------------------------------
// K4: affine grid + grid_sample of Embd1 with Mat.
// ---------------------------------------------------------------------------
__global__ __launch_bounds__(256) void k4_affine(const float* __restrict__ img, const float* __restrict__ mat,
                                                 float* __restrict__ out) {
    int n = blockIdx.x * 256 + threadIdx.x;
    if (n >= BB * CC * PIX) return;
    int pix = n % PIX;
    int bc  = n / PIX;
    int b   = bc >> 6;
    int i = pix / NPOL;
    int j = pix - i * NPOL;
    float xx = -1.0f + (float)j * (2.0f / 124.0f);
    float yy = -1.0f + (float)i * (2.0f / 124.0f);
    const float* M = mat + b * 6;
    float gx = M[0] * xx + M[1] * yy + M[2];
    float gy = M[3] * xx + M[4] * yy + M[5];
    float ix = (gx + 1.0f) * 0.5f * (float)(WW - 1);
    float iy = (gy + 1.0f) * 0.5f * (float)(HH - 1);
    float x0 = floorf(ix), y0 = floorf(iy);
    float x1 = x0 + 1.0f,  y1 = y0 + 1.0f;
    float wx0 = x1 - ix, wx1 = ix - x0;
    float wy0 = y1 - iy, wy1 = iy - y0;
    bool vx0 = (x0 >= 0.0f) && (x0 <= 127.0f);
    bool vx1 = (x1 >= 0.0f) && (x1 <= 127.0f);
    bool vy0 = (y0 >= 0.0f) && (y0 <= 127.0f);
    bool vy1 = (y1 >= 0.0f) && (y1 <= 127.0f);
    int xi0 = (int)fminf(fmaxf(x0, 0.0f), 127.0f);
    int xi1 = (int)fminf(fmaxf(x1, 0.0f), 127.0f);
    int yi0 = (int)fminf(fmaxf(y0, 0.0f), 127.0f);
    int yi1 = (int)fminf(fmaxf(y1, 0.0f), 127.0f);
    const float* plane = img + (size_t)bc * (HH * WW);
    float val = (wx0 * wy0 * (float)(vx0 && vy0)) * plane[yi0 * WW + xi0]
              + (wx1 * wy0 * (float)(vx1 && vy0)) * plane[yi0 * WW + xi1]
              + (wx0 * wy1 * (float)(vx0 && vy1)) * plane[yi1 * WW + xi0]
              + (wx1 * wy1 * (float)(vx1 && vy1)) * plane[yi1 * WW + xi1];
    out[n] = val;
}

// ---------------------------------------------------------------------------
// Launch. d_out: P1-pack u32[32M] (dead before k4) | Mat at float idx 32M.
// ws: P2-pack u32[32M] (128 MB) | scores f32[4032] | meta (~0.31 MB).
// ---------------------------------------------------------------------------
extern "C" void kernel_launch(void* const* d_in, const int* in_sizes, int n_in,
                              void* d_out, int out_size, void* d_ws, size_t ws_size,
                              hipStream_t stream) {
    const float* E1 = (const float*)d_in[0];
    const float* E2 = (const float*)d_in[1];
    float*    out    = (float*)d_out;
    unsigned* P1pk   = (unsigned*)d_out;          // 32,000,000 u32 = 128 MB
    float*    matOut = out + 32000000;            // 192 floats

    char*     ws     = (char*)d_ws;
    unsigned* P2pk   = (unsigned*)ws;                       // 128,000,000 B
    float*    scores = (float*)(ws + 128000000);            // 16,128 B
    char*     meta   = ws + 128000000 + 16384;
    int*   pk  = (int*)meta;
    float* w00 = (float*)(meta + 1 * 62500);
    float* w01 = (float*)(meta + 2 * 62500);
    float* w10 = (float*)(meta + 3 * 62500);
    float* w11 = (float*)(meta + 4 * 62500);

    k0_meta<<<(PIX + 255) / 256, 256, 0, stream>>>(pk, w00, w01, w10, w11);

    const int nElem = BB * CC * PIX;              // 32,000,000
    const int nBlk  = nElem / 256;                // 125,000
    k1_sample_pk<<<nBlk, 256, 0, stream>>>(E1, P1pk, pk, w00, w01, w10, w11);
    k1_sample_pk<<<nBlk, 256, 0, stream>>>(E2, P2pk, pk, w00, w01, w10, w11);

    kz_zero<<<(BB * NANG + 255) / 256, 256, 0, stream>>>(scores, BB * NANG);
    k2_gemm<<<BB * 8, 512, 0, stream>>>(P1pk, P2pk, scores);
    k3_theta<<<BB, 128, 0, stream>>>(scores, matOut);
    k4_affine<<<nBlk, 256, 0, stream>>>(E1, matOut, out);
}

// Round 3
// 481.617 us; speedup vs baseline: 2.5345x; 1.8387x over previous
//
#include <hip/hip_runtime.h>
#include <math.h>
#include <stdint.h>

#define NPOL 125
#define NANG 126
#define BB 32
#define CC 64
#define HH 128
#define WW 128
#define PIX (NPOL*NPOL)          // 15625
#define PI_F 3.14159265358979323846f

typedef __attribute__((ext_vector_type(8))) short bf16x8;
typedef __attribute__((ext_vector_type(4))) float f32x4;

// bf16 split helpers: v = hi + lo, each bf16 (RNE). Packed as (lo<<16)|hi in u32.
__device__ __forceinline__ unsigned f2bf(float f) {
    union { float f; unsigned u; } x; x.f = f;
    return (x.u + 0x7fffu + ((x.u >> 16) & 1u)) >> 16;
}
__device__ __forceinline__ float bf2f(unsigned h) {
    union { float f; unsigned u; } x; x.u = h << 16;
    return x.f;
}

// ---------------------------------------------------------------------------
// K0: per-pixel bilinear metadata for the polar grid (shared by all b,c).
// pk packs 4 clipped corner indices; w4 = (w00,w01,w10,w11) premasked weights.
// ---------------------------------------------------------------------------
__global__ __launch_bounds__(256) void k0_meta(int* __restrict__ pk, float4* __restrict__ w4) {
    int idx = blockIdx.x * 256 + threadIdx.x;
    if (idx >= PIX) return;
    int i = idx / NPOL;
    int j = idx - i * NPOL;
    float u = (float)j * (1.4142135623730951f / 124.0f);
    float v = -PI_F + (float)i * (2.0f * PI_F / 124.0f);
    float x = u * cosf(v);
    float y = u * sinf(v);
    float ix = (x + 1.0f) * 0.5f * (float)(WW - 1);
    float iy = (y + 1.0f) * 0.5f * (float)(HH - 1);
    float x0 = floorf(ix), y0 = floorf(iy);
    float x1 = x0 + 1.0f,  y1 = y0 + 1.0f;
    float wx0 = x1 - ix, wx1 = ix - x0;
    float wy0 = y1 - iy, wy1 = iy - y0;
    bool vx0 = (x0 >= 0.0f) && (x0 <= 127.0f);
    bool vx1 = (x1 >= 0.0f) && (x1 <= 127.0f);
    bool vy0 = (y0 >= 0.0f) && (y0 <= 127.0f);
    bool vy1 = (y1 >= 0.0f) && (y1 <= 127.0f);
    int xi0 = (int)fminf(fmaxf(x0, 0.0f), 127.0f);
    int xi1 = (int)fminf(fmaxf(x1, 0.0f), 127.0f);
    int yi0 = (int)fminf(fmaxf(y0, 0.0f), 127.0f);
    int yi1 = (int)fminf(fmaxf(y1, 0.0f), 127.0f);
    pk[idx] = xi0 | (yi0 << 8) | (xi1 << 16) | (yi1 << 24);
    float4 w;
    w.x = wx0 * wy0 * (float)(vx0 && vy0);
    w.y = wx1 * wy0 * (float)(vx1 && vy0);
    w.z = wx0 * wy1 * (float)(vx0 && vy1);
    w.w = wx1 * wy1 * (float)(vx1 && vy1);
    w4[idx] = w;
}

// ---------------------------------------------------------------------------
// K1: polar grid_sample -> split-bf16 packed u32. One block per (b,c) plane;
// whole 128x128 plane staged in LDS (coalesced float4), gather from LDS.
// ---------------------------------------------------------------------------
__global__ __launch_bounds__(512) void k1_sample_pk(const float* __restrict__ img, unsigned* __restrict__ out,
                                                    const int* __restrict__ pk, const float4* __restrict__ w4) {
    __shared__ float plane[HH * WW];
    const int bc  = blockIdx.x;
    const int tid = threadIdx.x;
    const float4* src = (const float4*)img + (size_t)bc * (HH * WW / 4);
    float4* d4 = (float4*)plane;
    #pragma unroll
    for (int it = 0; it < 8; ++it) d4[it * 512 + tid] = src[it * 512 + tid];
    __syncthreads();
    const int base = bc * PIX;
    for (int pix = tid; pix < PIX; pix += 512) {
        int p = pk[pix];
        float4 w = w4[pix];
        int xi0 = p & 255, yi0 = (p >> 8) & 255, xi1 = (p >> 16) & 255, yi1 = (p >> 24) & 255;
        float val = w.x * plane[yi0 * WW + xi0]
                  + w.y * plane[yi0 * WW + xi1]
                  + w.z * plane[yi1 * WW + xi0]
                  + w.w * plane[yi1 * WW + xi1];
        unsigned hb = f2bf(val);
        unsigned lb = f2bf(val - bf2f(hb));
        out[base + pix] = (lb << 16) | hb;
    }
}

// ---------------------------------------------------------------------------
// KZ: zero the scores accumulator.
// ---------------------------------------------------------------------------
__global__ __launch_bounds__(256) void kz_zero(float* __restrict__ p, int n) {
    int i = blockIdx.x * 256 + threadIdx.x;
    if (i < n) p[i] = 0.0f;
}

// ---------------------------------------------------------------------------
// K2: correlation as register-blocked MFMA "GEMM", no LDS tiles, no barriers.
// Per b: R[r,i] = sum_k aug[r,k]*P2[i,k] over k=(c,j); scores[b,t] = band sum
// over t = r - i. A and B fragments are loaded DIRECTLY from global (L2-hot
// slabs); out-of-range rows/cols load exact 0 so the epilogue needs no
// element guards. Grid: 1024 blocks = 32b x 2mt x 16kc (4 channels each),
// XCD-grouped so the 4 blocks sharing planes land on one XCD's L2.
// Block: 256 thr = 4 waves (2M x 2N), wave tile 64x64, acc 4x4, BK=32 u32,
// 3-pass split-bf16 (AhBh + AhBl + AlBh).
// ---------------------------------------------------------------------------
__global__ __launch_bounds__(256, 3) void k2_gemm(const unsigned* __restrict__ P1, const unsigned* __restrict__ P2,
                                                  float* __restrict__ scores) {
    __shared__ float sd[128];
    // XCD grouping: members m=0..3 of group q are 256 apart in blockIdx -> same
    // bid%8 (same XCD under round-robin dispatch), sharing plane slabs in L2.
    const int bid = blockIdx.x;
    const int q = bid & 255, m = bid >> 8;
    const int bh  = q >> 4, kc0 = q & 15;
    const int b   = (m & 2) ? (BB - 1 - bh) : bh;
    const int kc  = (m & 2) ? (15 - kc0) : kc0;
    const int mt  = m & 1;

    const int tid  = threadIdx.x;
    const int lane = tid & 63;
    const int wid  = tid >> 6;
    const int wm   = wid >> 1;            // 0..1
    const int wn   = wid & 1;             // 0..1
    const int frow = lane & 15;
    const int fk8  = (lane >> 4) << 3;    // 0,8,16,24

    if (tid < 128) sd[tid] = 0.0f;

    f32x4 acc[4][4];
    #pragma unroll
    for (int mi = 0; mi < 4; ++mi)
        #pragma unroll
        for (int ni = 0; ni < 4; ++ni) acc[mi][ni] = (f32x4){0.f, 0.f, 0.f, 0.f};

    // Per-lane A rows (aug row index) and B rows (i index) — fixed all K-steps.
    int rA[4], iB[4];
    bool okA[4], okB[4];
    #pragma unroll
    for (int x = 0; x < 4; ++x) {
        rA[x] = mt * 128 + wm * 64 + x * 16 + frow;
        okA[x] = rA[x] < 250;
        iB[x] = wn * 64 + x * 16 + frow;
        okB[x] = iB[x] < NPOL;
    }

    for (int cl = 0; cl < 4; ++cl) {
        const int c  = kc * 4 + cl;
        const int pD = (b * CC + c) * PIX;                          // direct plane (P1 & P2)
        const int pF = ((BB - 1 - b) * CC + (CC - 1 - c)) * PIX;    // flipped plane (P1)
        int baseA[4], baseB[4];
        #pragma unroll
        for (int x = 0; x < 4; ++x) {
            int bA = (rA[x] < NPOL) ? (pD + rA[x] * NPOL) : (pF + (rA[x] - NPOL) * NPOL);
            baseA[x] = okA[x] ? bA : 0;
            baseB[x] = okB[x] ? (pD + iB[x] * NPOL) : 0;
        }

        #pragma unroll
        for (int jc = 0; jc < 4; ++jc) {
            const int j0 = jc * 32;
            const bool edge = (jc == 3);       // j0=96: cols 96..127, j>=125 invalid

            bf16x8 bhv[4], blv[4];
            #pragma unroll
            for (int ni = 0; ni < 4; ++ni) {
                unsigned w[8];
                #pragma unroll
                for (int e = 0; e < 8; ++e) {
                    bool ok = okB[ni] && (!edge || (j0 + fk8 + e) < NPOL);
                    w[e] = ok ? P2[baseB[ni] + j0 + fk8 + e] : 0u;
                }
                #pragma unroll
                for (int e = 0; e < 8; ++e) {
                    bhv[ni][e] = (short)(w[e] & 0xffffu);
                    blv[ni][e] = (short)(w[e] >> 16);
                }
            }

            #pragma unroll
            for (int mi = 0; mi < 4; ++mi) {
                unsigned w[8];
                #pragma unroll
                for (int e = 0; e < 8; ++e) {
                    bool ok = okA[mi] && (!edge || (j0 + fk8 + e) < NPOL);
                    w[e] = ok ? P1[baseA[mi] + j0 + fk8 + e] : 0u;
                }
                bf16x8 ah, al;
                #pragma unroll
                for (int e = 0; e < 8; ++e) {
                    ah[e] = (short)(w[e] & 0xffffu);
                    al[e] = (short)(w[e] >> 16);
                }
                #pragma unroll
                for (int ni = 0; ni < 4; ++ni) {
                    acc[mi][ni] = __builtin_amdgcn_mfma_f32_16x16x32_bf16(ah, bhv[ni], acc[mi][ni], 0, 0, 0);
                    acc[mi][ni] = __builtin_amdgcn_mfma_f32_16x16x32_bf16(ah, blv[ni], acc[mi][ni], 0, 0, 0);
                    acc[mi][ni] = __builtin_amdgcn_mfma_f32_16x16x32_bf16(al, bhv[ni], acc[mi][ni], 0, 0, 0);
                }
            }
        }
    }

    // Per-thread partial reduce over equal t = r - i (d = mi - ni), then LDS.
    float part[7][4];
    #pragma unroll
    for (int d = 0; d < 7; ++d)
        #pragma unroll
        for (int r = 0; r < 4; ++r) part[d][r] = 0.0f;
    #pragma unroll
    for (int mi = 0; mi < 4; ++mi)
        #pragma unroll
        for (int ni = 0; ni < 4; ++ni) {
            const int d = mi - ni + 3;
            #pragma unroll
            for (int r = 0; r < 4; ++r) part[d][r] += acc[mi][ni][r];
        }

    __syncthreads();   // sd zeros visible
    const int rB0 = mt * 128 + wm * 64 + ((lane >> 4) << 2);
    const int iB0 = wn * 64 + frow;
    #pragma unroll
    for (int d = 0; d < 7; ++d)
        #pragma unroll
        for (int r = 0; r < 4; ++r) {
            int t = rB0 - iB0 + (d - 3) * 16 + r;
            if (t >= 0 && t < NANG) atomicAdd(&sd[t], part[d][r]);
        }
    __syncthreads();
    if (tid < NANG) atomicAdd(&scores[b * NANG + tid], sd[tid]);
}

// ---------------------------------------------------------------------------
// K3: softmax over t, theta -> Mat. One block per b.
// ---------------------------------------------------------------------------
__global__ __launch_bounds__(128) void k3_theta(const float* __restrict__ scores, float* __restrict__ matOut) {
    const int b = blockIdx.x;
    const int t = threadIdx.x;   // 0..127
    __shared__ float sd[128];
    __shared__ float red[128];

    float sval = (t < NANG) ? scores[b * NANG + t] : -1e30f;
    sd[t]  = sval;
    red[t] = sval;
    __syncthreads();
    for (int st = 64; st > 0; st >>= 1) {
        if (t < st) red[t] = fmaxf(red[t], red[t + st]);
        __syncthreads();
    }
    const float m = red[0];
    __syncthreads();
    const float e = (t < NANG) ? expf(sd[t] - m) : 0.0f;
    red[t] = e;
    __syncthreads();
    for (int st = 64; st > 0; st >>= 1) {
        if (t < st) red[t] += red[t + st];
        __syncthreads();
    }
    const float Z = red[0];
    __syncthreads();
    const float ang = -PI_F + (float)t * (2.0f * PI_F / 125.0f);
    red[t] = e * ang;
    __syncthreads();
    for (int st = 64; st > 0; st >>= 1) {
        if (t < st) red[t] += red[t + st];
        __syncthreads();
    }
    if (t == 0) {
        float theta = red[0] / Z - PI_F;
        float cth = cosf(theta), sth = sinf(theta);
        float* M = matOut + b * 6;
        M[0] = cth; M[1] = -sth; M[2] = 0.0f;
        M[3] = sth; M[4] = cth;  M[5] = 0.0f;
    }
}

// ---------------------------------------------------------------------------
// K4: affine grid + grid_sample of Embd1. One block per (b,c) plane; plane
// staged in LDS (coalesced), bilinear gather from LDS, streamed write.
// ---------------------------------------------------------------------------
__global__ __launch_bounds__(512) void k4_affine(const float* __restrict__ img, const float* __restrict__ mat,
                                                 float* __restrict__ out) {
    __shared__ float plane[HH * WW];
    const int bc  = blockIdx.x;
    const int b   = bc >> 6;
    const int tid = threadIdx.x;
    const float4* src = (const float4*)img + (size_t)bc * (HH * WW / 4);
    float4* d4 = (float4*)plane;
    #pragma unroll
    for (int it = 0; it < 8; ++it) d4[it * 512 + tid] = src[it * 512 + tid];
    __syncthreads();
    const float M0 = mat[b * 6 + 0], M1 = mat[b * 6 + 1];
    const float M3 = mat[b * 6 + 3], M4 = mat[b * 6 + 4];
    const int base = bc * PIX;
    for (int pix = tid; pix < PIX; pix += 512) {
        int i = pix / NPOL;
        int j = pix - i * NPOL;
        float xx = -1.0f + (float)j * (2.0f / 124.0f);
        float yy = -1.0f + (float)i * (2.0f / 124.0f);
        float gx = M0 * xx + M1 * yy;
        float gy = M3 * xx + M4 * yy;
        float ix = (gx + 1.0f) * 0.5f * (float)(WW - 1);
        float iy = (gy + 1.0f) * 0.5f * (float)(HH - 1);
        float x0 = floorf(ix), y0 = floorf(iy);
        float x1 = x0 + 1.0f,  y1 = y0 + 1.0f;
        float wx0 = x1 - ix, wx1 = ix - x0;
        float wy0 = y1 - iy, wy1 = iy - y0;
        bool vx0 = (x0 >= 0.0f) && (x0 <= 127.0f);
        bool vx1 = (x1 >= 0.0f) && (x1 <= 127.0f);
        bool vy0 = (y0 >= 0.0f) && (y0 <= 127.0f);
        bool vy1 = (y1 >= 0.0f) && (y1 <= 127.0f);
        int xi0 = (int)fminf(fmaxf(x0, 0.0f), 127.0f);
        int xi1 = (int)fminf(fmaxf(x1, 0.0f), 127.0f);
        int yi0 = (int)fminf(fmaxf(y0, 0.0f), 127.0f);
        int yi1 = (int)fminf(fmaxf(y1, 0.0f), 127.0f);
        float val = (wx0 * wy0 * (float)(vx0 && vy0)) * plane[yi0 * WW + xi0]
                  + (wx1 * wy0 * (float)(vx1 && vy0)) * plane[yi0 * WW + xi1]
                  + (wx0 * wy1 * (float)(vx0 && vy1)) * plane[yi1 * WW + xi0]
                  + (wx1 * wy1 * (float)(vx1 && vy1)) * plane[yi1 * WW + xi1];
        out[base + pix] = val;
    }
}

// ---------------------------------------------------------------------------
// Launch. d_out: P1-pack u32[32M] (dead before k4) | Mat at float idx 32M.
// ws: P2-pack (128 MB) | scores (16 KB pad) | pk (64 KB pad) | w4 (250 KB).
// ---------------------------------------------------------------------------
extern "C" void kernel_launch(void* const* d_in, const int* in_sizes, int n_in,
                              void* d_out, int out_size, void* d_ws, size_t ws_size,
                              hipStream_t stream) {
    const float* E1 = (const float*)d_in[0];
    const float* E2 = (const float*)d_in[1];
    float*    out    = (float*)d_out;
    unsigned* P1pk   = (unsigned*)d_out;          // 32,000,000 u32 = 128 MB
    float*    matOut = out + 32000000;            // 192 floats

    char*     ws     = (char*)d_ws;
    unsigned* P2pk   = (unsigned*)ws;                         // 128,000,000 B
    float*    scores = (float*)(ws + 128000000);              // 16,384 B pad
    int*      pk     = (int*)(ws + 128016384);                // 64,000 B pad
    float4*   w4     = (float4*)(ws + 128080384);             // 250,000 B

    k0_meta<<<(PIX + 255) / 256, 256, 0, stream>>>(pk, w4);

    k1_sample_pk<<<BB * CC, 512, 0, stream>>>(E1, P1pk, pk, w4);
    k1_sample_pk<<<BB * CC, 512, 0, stream>>>(E2, P2pk, pk, w4);

    kz_zero<<<(BB * NANG + 255) / 256, 256, 0, stream>>>(scores, BB * NANG);
    k2_gemm<<<1024, 256, 0, stream>>>(P1pk, P2pk, scores);
    k3_theta<<<BB, 128, 0, stream>>>(scores, matOut);
    k4_affine<<<BB * CC, 512, 0, stream>>>(E1, matOut, out);
}

// Round 4
// 417.372 us; speedup vs baseline: 2.9246x; 1.1539x over previous
//
#include <hip/hip_runtime.h>
#include <math.h>
#include <stdint.h>

#define NPOL 125
#define NANG 126
#define BB 32
#define CC 64
#define HH 128
#define WW 128
#define PIX (NPOL*NPOL)          // 15625
#define PI_F 3.14159265358979323846f

// Padded plane: 125 rows x 128 u32 (512B). Row = [32 u32 hi-pairs | 32 u32 lo-pairs]... 
// actually row = 64 u32 hi region? NO: row = 128 u32 total: u32 0..63 = fp16-hi pairs
// (cols 0..127, 2 cols/u32), u32 64..127 = fp16-lo pairs. Cols 125..127 zero.
#define PLANE_U32 16000          // 125 * 128
#define P1_SPLIT 2000            // planes 0..1999 in d_out, rest in ws tail

typedef __attribute__((ext_vector_type(4))) float f32x4;
typedef _Float16 f16x8 __attribute__((ext_vector_type(8)));
union U16 { uint4 u; f16x8 v; };

// ---------------------------------------------------------------------------
// K0: per-pixel bilinear metadata for the polar grid (shared by all b,c).
// ---------------------------------------------------------------------------
__global__ __launch_bounds__(256) void k0_meta(int* __restrict__ pk, float4* __restrict__ w4) {
    int idx = blockIdx.x * 256 + threadIdx.x;
    if (idx >= PIX) return;
    int i = idx / NPOL;
    int j = idx - i * NPOL;
    float u = (float)j * (1.4142135623730951f / 124.0f);
    float v = -PI_F + (float)i * (2.0f * PI_F / 124.0f);
    float x = u * cosf(v);
    float y = u * sinf(v);
    float ix = (x + 1.0f) * 0.5f * (float)(WW - 1);
    float iy = (y + 1.0f) * 0.5f * (float)(HH - 1);
    float x0 = floorf(ix), y0 = floorf(iy);
    float x1 = x0 + 1.0f,  y1 = y0 + 1.0f;
    float wx0 = x1 - ix, wx1 = ix - x0;
    float wy0 = y1 - iy, wy1 = iy - y0;
    bool vx0 = (x0 >= 0.0f) && (x0 <= 127.0f);
    bool vx1 = (x1 >= 0.0f) && (x1 <= 127.0f);
    bool vy0 = (y0 >= 0.0f) && (y0 <= 127.0f);
    bool vy1 = (y1 >= 0.0f) && (y1 <= 127.0f);
    int xi0 = (int)fminf(fmaxf(x0, 0.0f), 127.0f);
    int xi1 = (int)fminf(fmaxf(x1, 0.0f), 127.0f);
    int yi0 = (int)fminf(fmaxf(y0, 0.0f), 127.0f);
    int yi1 = (int)fminf(fmaxf(y1, 0.0f), 127.0f);
    pk[idx] = xi0 | (yi0 << 8) | (xi1 << 16) | (yi1 << 24);
    float4 w;
    w.x = wx0 * wy0 * (float)(vx0 && vy0);
    w.y = wx1 * wy0 * (float)(vx1 && vy0);
    w.z = wx0 * wy1 * (float)(vx0 && vy1);
    w.w = wx1 * wy1 * (float)(vx1 && vy1);
    w4[idx] = w;
}

// ---------------------------------------------------------------------------
// K1: polar grid_sample -> padded split-fp16 plane layout (MFMA-ready).
// One block per (b,c) plane; image plane staged in LDS, bilinear from LDS.
// ---------------------------------------------------------------------------
__global__ __launch_bounds__(512) void k1_sample(const float* __restrict__ img,
                                                 unsigned* __restrict__ dst0, unsigned* __restrict__ dst1,
                                                 int splitPlane,
                                                 const int* __restrict__ pk, const float4* __restrict__ w4) {
    __shared__ float plane[HH * WW];
    const int pl  = blockIdx.x;
    const int tid = threadIdx.x;
    const float4* src = (const float4*)img + (size_t)pl * (HH * WW / 4);
    float4* d4 = (float4*)plane;
    #pragma unroll
    for (int it = 0; it < 8; ++it) d4[it * 512 + tid] = src[it * 512 + tid];
    __syncthreads();

    unsigned* dst = (pl < splitPlane) ? (dst0 + (size_t)pl * PLANE_U32)
                                      : (dst1 + (size_t)(pl - splitPlane) * PLANE_U32);
    for (int s = tid; s < 125 * 64; s += 512) {
        const int r = s >> 6;          // 0..124
        const int p = s & 63;          // u32 pair slot; cols 2p, 2p+1
        float v0 = 0.0f, v1 = 0.0f;
        const int j0 = 2 * p, j1 = 2 * p + 1;
        if (j0 < NPOL) {
            int pix = r * NPOL + j0;
            int pp = pk[pix]; float4 w = w4[pix];
            int xi0 = pp & 255, yi0 = (pp >> 8) & 255, xi1 = (pp >> 16) & 255, yi1 = (pp >> 24) & 255;
            v0 = w.x * plane[yi0 * WW + xi0] + w.y * plane[yi0 * WW + xi1]
               + w.z * plane[yi1 * WW + xi0] + w.w * plane[yi1 * WW + xi1];
        }
        if (j1 < NPOL) {
            int pix = r * NPOL + j1;
            int pp = pk[pix]; float4 w = w4[pix];
            int xi0 = pp & 255, yi0 = (pp >> 8) & 255, xi1 = (pp >> 16) & 255, yi1 = (pp >> 24) & 255;
            v1 = w.x * plane[yi0 * WW + xi0] + w.y * plane[yi0 * WW + xi1]
               + w.z * plane[yi1 * WW + xi0] + w.w * plane[yi1 * WW + xi1];
        }
        _Float16 h0 = (_Float16)v0; _Float16 l0 = (_Float16)(v0 - (float)h0);
        _Float16 h1 = (_Float16)v1; _Float16 l1 = (_Float16)(v1 - (float)h1);
        unsigned hw = (unsigned)__builtin_bit_cast(unsigned short, h0)
                    | ((unsigned)__builtin_bit_cast(unsigned short, h1) << 16);
        unsigned lw = (unsigned)__builtin_bit_cast(unsigned short, l0)
                    | ((unsigned)__builtin_bit_cast(unsigned short, l1) << 16);
        dst[r * 128 + p]      = hw;
        dst[r * 128 + 64 + p] = lw;
    }
}

// ---------------------------------------------------------------------------
// KZ: zero scores (4032 f32) + zero page (128 u32), contiguous.
// ---------------------------------------------------------------------------
__global__ __launch_bounds__(256) void kz_zero(float* __restrict__ p, int n) {
    int i = blockIdx.x * 256 + threadIdx.x;
    if (i < n) p[i] = 0.0f;
}

// ---------------------------------------------------------------------------
// K2: correlation as register-blocked MFMA GEMM. All fragment loads are single
// aligned dwordx4 (padded planes, zero-page row guards), zero unpack VALU.
// Grid 1024 = 32b x 2mt x 16kc(4ch), XCD-grouped (4 partner blocks 256 apart).
// Block 256 thr = 4 waves (2M x 2N), wave tile 64x64, 3-pass split-fp16.
// ---------------------------------------------------------------------------
__global__ __launch_bounds__(256, 3) void k2_gemm(const unsigned* __restrict__ P1m,
                                                  const unsigned* __restrict__ P1t,
                                                  const unsigned* __restrict__ P2,
                                                  const unsigned* __restrict__ zp,
                                                  float* __restrict__ scores) {
    __shared__ float sd[128];
    const int bid = blockIdx.x;
    const int q = bid & 255, m = bid >> 8;
    const int bh  = q >> 4, kc0 = q & 15;
    const int b   = (m & 2) ? (BB - 1 - bh) : bh;
    const int kc  = (m & 2) ? (15 - kc0) : kc0;
    const int mt  = m & 1;

    const int tid  = threadIdx.x;
    const int lane = tid & 63;
    const int wid  = tid >> 6;
    const int wm   = wid >> 1;            // 0..1
    const int wn   = wid & 1;             // 0..1
    const int frow = lane & 15;
    const int kq4  = (lane >> 4) << 2;    // k-group offset in u32 pairs: 0,4,8,12

    if (tid < 128) sd[tid] = 0.0f;

    f32x4 acc[4][4];
    #pragma unroll
    for (int mi = 0; mi < 4; ++mi)
        #pragma unroll
        for (int ni = 0; ni < 4; ++ni) acc[mi][ni] = (f32x4){0.f, 0.f, 0.f, 0.f};

    int rA[4], iB[4];
    #pragma unroll
    for (int x = 0; x < 4; ++x) {
        rA[x] = mt * 128 + wm * 64 + x * 16 + frow;   // aug row 0..255
        iB[x] = wn * 64 + x * 16 + frow;              // i 0..127
    }

    for (int cl = 0; cl < 4; ++cl) {
        const int c   = kc * 4 + cl;
        const int plD = b * CC + c;
        const int plF = (BB - 1 - b) * CC + (CC - 1 - c);
        const unsigned* pD1 = (plD < P1_SPLIT) ? (P1m + (size_t)plD * PLANE_U32)
                                               : (P1t + (size_t)(plD - P1_SPLIT) * PLANE_U32);
        const unsigned* pF1 = (plF < P1_SPLIT) ? (P1m + (size_t)plF * PLANE_U32)
                                               : (P1t + (size_t)(plF - P1_SPLIT) * PLANE_U32);
        const unsigned* pD2 = P2 + (size_t)plD * PLANE_U32;

        const unsigned* rowA[4];
        const unsigned* rowB[4];
        #pragma unroll
        for (int x = 0; x < 4; ++x) {
            rowA[x] = (rA[x] < NPOL) ? (pD1 + rA[x] * 128 + kq4)
                    : ((rA[x] < 250) ? (pF1 + (rA[x] - NPOL) * 128 + kq4) : (zp + kq4));
            rowB[x] = (iB[x] < NPOL) ? (pD2 + iB[x] * 128 + kq4) : (zp + kq4);
        }

        #pragma unroll
        for (int jc = 0; jc < 4; ++jc) {
            const int off = jc * 16;     // u32: 32 cols per jc chunk / 2 cols per u32
            U16 bhv[4], blv[4];
            #pragma unroll
            for (int ni = 0; ni < 4; ++ni) {
                bhv[ni].u = *(const uint4*)(rowB[ni] + off);
                blv[ni].u = *(const uint4*)(rowB[ni] + off + 64);
            }
            #pragma unroll
            for (int mi = 0; mi < 4; ++mi) {
                U16 ah, al;
                ah.u = *(const uint4*)(rowA[mi] + off);
                al.u = *(const uint4*)(rowA[mi] + off + 64);
                #pragma unroll
                for (int ni = 0; ni < 4; ++ni) {
                    acc[mi][ni] = __builtin_amdgcn_mfma_f32_16x16x32_f16(ah.v, bhv[ni].v, acc[mi][ni], 0, 0, 0);
                    acc[mi][ni] = __builtin_amdgcn_mfma_f32_16x16x32_f16(ah.v, blv[ni].v, acc[mi][ni], 0, 0, 0);
                    acc[mi][ni] = __builtin_amdgcn_mfma_f32_16x16x32_f16(al.v, bhv[ni].v, acc[mi][ni], 0, 0, 0);
                }
            }
        }
    }

    // Per-thread partial reduce over equal t = r - i (d = mi - ni), then LDS.
    float part[7][4];
    #pragma unroll
    for (int d = 0; d < 7; ++d)
        #pragma unroll
        for (int r = 0; r < 4; ++r) part[d][r] = 0.0f;
    #pragma unroll
    for (int mi = 0; mi < 4; ++mi)
        #pragma unroll
        for (int ni = 0; ni < 4; ++ni) {
            const int d = mi - ni + 3;
            #pragma unroll
            for (int r = 0; r < 4; ++r) part[d][r] += acc[mi][ni][r];
        }

    __syncthreads();   // sd zeros visible
    const int rB0 = mt * 128 + wm * 64 + ((lane >> 4) << 2);
    const int iB0 = wn * 64 + frow;
    #pragma unroll
    for (int d = 0; d < 7; ++d)
        #pragma unroll
        for (int r = 0; r < 4; ++r) {
            int t = rB0 - iB0 + (d - 3) * 16 + r;
            if (t >= 0 && t < NANG) atomicAdd(&sd[t], part[d][r]);
        }
    __syncthreads();
    if (tid < NANG) atomicAdd(&scores[b * NANG + tid], sd[tid]);
}

// ---------------------------------------------------------------------------
// K3: softmax over t, theta -> Mat. One block per b.
// ---------------------------------------------------------------------------
__global__ __launch_bounds__(128) void k3_theta(const float* __restrict__ scores, float* __restrict__ matOut) {
    const int b = blockIdx.x;
    const int t = threadIdx.x;   // 0..127
    __shared__ float sd[128];
    __shared__ float red[128];

    float sval = (t < NANG) ? scores[b * NANG + t] : -1e30f;
    sd[t]  = sval;
    red[t] = sval;
    __syncthreads();
    for (int st = 64; st > 0; st >>= 1) {
        if (t < st) red[t] = fmaxf(red[t], red[t + st]);
        __syncthreads();
    }
    const float m = red[0];
    __syncthreads();
    const float e = (t < NANG) ? expf(sd[t] - m) : 0.0f;
    red[t] = e;
    __syncthreads();
    for (int st = 64; st > 0; st >>= 1) {
        if (t < st) red[t] += red[t + st];
        __syncthreads();
    }
    const float Z = red[0];
    __syncthreads();
    const float ang = -PI_F + (float)t * (2.0f * PI_F / 125.0f);
    red[t] = e * ang;
    __syncthreads();
    for (int st = 64; st > 0; st >>= 1) {
        if (t < st) red[t] += red[t + st];
        __syncthreads();
    }
    if (t == 0) {
        float theta = red[0] / Z - PI_F;
        float cth = cosf(theta), sth = sinf(theta);
        float* M = matOut + b * 6;
        M[0] = cth; M[1] = -sth; M[2] = 0.0f;
        M[3] = sth; M[4] = cth;  M[5] = 0.0f;
    }
}

// ---------------------------------------------------------------------------
// K4: affine grid + grid_sample of Embd1. One block per (b,c) plane.
// ---------------------------------------------------------------------------
__global__ __launch_bounds__(512) void k4_affine(const float* __restrict__ img, const float* __restrict__ mat,
                                                 float* __restrict__ out) {
    __shared__ float plane[HH * WW];
    const int bc  = blockIdx.x;
    const int b   = bc >> 6;
    const int tid = threadIdx.x;
    const float4* src = (const float4*)img + (size_t)bc * (HH * WW / 4);
    float4* d4 = (float4*)plane;
    #pragma unroll
    for (int it = 0; it < 8; ++it) d4[it * 512 + tid] = src[it * 512 + tid];
    __syncthreads();
    const float M0 = mat[b * 6 + 0], M1 = mat[b * 6 + 1];
    const float M3 = mat[b * 6 + 3], M4 = mat[b * 6 + 4];
    const int base = bc * PIX;
    for (int pix = tid; pix < PIX; pix += 512) {
        int i = pix / NPOL;
        int j = pix - i * NPOL;
        float xx = -1.0f + (float)j * (2.0f / 124.0f);
        float yy = -1.0f + (float)i * (2.0f / 124.0f);
        float gx = M0 * xx + M1 * yy;
        float gy = M3 * xx + M4 * yy;
        float ix = (gx + 1.0f) * 0.5f * (float)(WW - 1);
        float iy = (gy + 1.0f) * 0.5f * (float)(HH - 1);
        float x0 = floorf(ix), y0 = floorf(iy);
        float x1 = x0 + 1.0f,  y1 = y0 + 1.0f;
        float wx0 = x1 - ix, wx1 = ix - x0;
        float wy0 = y1 - iy, wy1 = iy - y0;
        bool vx0 = (x0 >= 0.0f) && (x0 <= 127.0f);
        bool vx1 = (x1 >= 0.0f) && (x1 <= 127.0f);
        bool vy0 = (y0 >= 0.0f) && (y0 <= 127.0f);
        bool vy1 = (y1 >= 0.0f) && (y1 <= 127.0f);
        int xi0 = (int)fminf(fmaxf(x0, 0.0f), 127.0f);
        int xi1 = (int)fminf(fmaxf(x1, 0.0f), 127.0f);
        int yi0 = (int)fminf(fmaxf(y0, 0.0f), 127.0f);
        int yi1 = (int)fminf(fmaxf(y1, 0.0f), 127.0f);
        float val = (wx0 * wy0 * (float)(vx0 && vy0)) * plane[yi0 * WW + xi0]
                  + (wx1 * wy0 * (float)(vx1 && vy0)) * plane[yi0 * WW + xi1]
                  + (wx0 * wy1 * (float)(vx0 && vy1)) * plane[yi1 * WW + xi0]
                  + (wx1 * wy1 * (float)(vx1 && vy1)) * plane[yi1 * WW + xi1];
        out[base + pix] = val;
    }
}

// ---------------------------------------------------------------------------
// Layout.
// d_out: P1pad planes 0..1999 (128,000,000 B) | Mat at float idx 32,000,000.
// ws: P2pad 2048 planes (131,072,000) | P1 tail 48 planes (3,072,000) |
//     scores 4032 f32 | zeropage 128 u32 | pk 250,000 | w4 250,000.
// ---------------------------------------------------------------------------
#define OFF_P1T 131072000
#define OFF_SC  134144000
#define OFF_ZP  134160128
#define OFF_PK  134160640
#define OFF_W4  134410640

extern "C" void kernel_launch(void* const* d_in, const int* in_sizes, int n_in,
                              void* d_out, int out_size, void* d_ws, size_t ws_size,
                              hipStream_t stream) {
    const float* E1 = (const float*)d_in[0];
    const float* E2 = (const float*)d_in[1];
    float*    out    = (float*)d_out;
    unsigned* P1m    = (unsigned*)d_out;           // planes 0..1999
    float*    matOut = out + 32000000;             // 192 floats

    char*     ws     = (char*)d_ws;
    unsigned* P2pd   = (unsigned*)ws;
    unsigned* P1t    = (unsigned*)(ws + OFF_P1T);
    float*    scores = (float*)(ws + OFF_SC);
    unsigned* zp     = (unsigned*)(ws + OFF_ZP);
    int*      pk     = (int*)(ws + OFF_PK);
    float4*   w4     = (float4*)(ws + OFF_W4);

    k0_meta<<<(PIX + 255) / 256, 256, 0, stream>>>(pk, w4);

    k1_sample<<<BB * CC, 512, 0, stream>>>(E1, P1m, P1t, P1_SPLIT, pk, w4);
    k1_sample<<<BB * CC, 512, 0, stream>>>(E2, P2pd, P2pd, 2048, pk, w4);

    kz_zero<<<(4160 + 255) / 256, 256, 0, stream>>>(scores, 4160);  // scores + zero page
    k2_gemm<<<1024, 256, 0, stream>>>(P1m, P1t, P2pd, zp, scores);
    k3_theta<<<BB, 128, 0, stream>>>(scores, matOut);
    k4_affine<<<BB * CC, 512, 0, stream>>>(E1, matOut, out);
}

// Round 5
// 410.052 us; speedup vs baseline: 2.9768x; 1.0179x over previous
//
#include <hip/hip_runtime.h>
#include <math.h>
#include <stdint.h>

#define NPOL 125
#define NANG 126
#define BB 32
#define CC 64
#define HH 128
#define WW 128
#define PIX (NPOL*NPOL)          // 15625
#define PI_F 3.14159265358979323846f

// Padded plane: 125 rows x 128 u32 (512B/row). Row u32 0..63 = fp16-hi pairs
// (cols 0..127, 2 cols per u32), u32 64..127 = fp16-lo pairs. Cols 125..127 = 0.
#define PLANE_U32 16000          // 125 * 128
#define P1_SPLIT 2000            // planes 0..1999 in d_out, rest in ws tail

typedef __attribute__((ext_vector_type(4))) float f32x4;
typedef _Float16 f16x8 __attribute__((ext_vector_type(8)));
union U16 { uint4 u; f16x8 v; };

// ---------------------------------------------------------------------------
// K0: per-pixel bilinear metadata for the polar grid (shared by all b,c).
// ---------------------------------------------------------------------------
__global__ __launch_bounds__(256) void k0_meta(int* __restrict__ pk, float4* __restrict__ w4) {
    int idx = blockIdx.x * 256 + threadIdx.x;
    if (idx >= PIX) return;
    int i = idx / NPOL;
    int j = idx - i * NPOL;
    float u = (float)j * (1.4142135623730951f / 124.0f);
    float v = -PI_F + (float)i * (2.0f * PI_F / 124.0f);
    float x = u * cosf(v);
    float y = u * sinf(v);
    float ix = (x + 1.0f) * 0.5f * (float)(WW - 1);
    float iy = (y + 1.0f) * 0.5f * (float)(HH - 1);
    float x0 = floorf(ix), y0 = floorf(iy);
    float x1 = x0 + 1.0f,  y1 = y0 + 1.0f;
    float wx0 = x1 - ix, wx1 = ix - x0;
    float wy0 = y1 - iy, wy1 = iy - y0;
    bool vx0 = (x0 >= 0.0f) && (x0 <= 127.0f);
    bool vx1 = (x1 >= 0.0f) && (x1 <= 127.0f);
    bool vy0 = (y0 >= 0.0f) && (y0 <= 127.0f);
    bool vy1 = (y1 >= 0.0f) && (y1 <= 127.0f);
    int xi0 = (int)fminf(fmaxf(x0, 0.0f), 127.0f);
    int xi1 = (int)fminf(fmaxf(x1, 0.0f), 127.0f);
    int yi0 = (int)fminf(fmaxf(y0, 0.0f), 127.0f);
    int yi1 = (int)fminf(fmaxf(y1, 0.0f), 127.0f);
    pk[idx] = xi0 | (yi0 << 8) | (xi1 << 16) | (yi1 << 24);
    float4 w;
    w.x = wx0 * wy0 * (float)(vx0 && vy0);
    w.y = wx1 * wy0 * (float)(vx1 && vy0);
    w.z = wx0 * wy1 * (float)(vx0 && vy1);
    w.w = wx1 * wy1 * (float)(vx1 && vy1);
    w4[idx] = w;
}

// ---------------------------------------------------------------------------
// K1: polar grid_sample -> padded split-fp16 plane layout (MFMA-ready).
// One block per plane; planes 0..2047 sample E1, 2048..4095 sample E2.
// Image plane staged in LDS, bilinear gather from LDS.
// ---------------------------------------------------------------------------
__global__ __launch_bounds__(512) void k1_sample(const float* __restrict__ E1, const float* __restrict__ E2,
                                                 unsigned* __restrict__ P1m, unsigned* __restrict__ P1t,
                                                 unsigned* __restrict__ P2,
                                                 const int* __restrict__ pk, const float4* __restrict__ w4) {
    __shared__ float plane[HH * WW];
    const int gpl = blockIdx.x;          // 0..4095
    const int tid = threadIdx.x;
    const bool isE2 = gpl >= 2048;
    const int pl = isE2 ? (gpl - 2048) : gpl;
    const float* img = isE2 ? E2 : E1;
    const float4* src = (const float4*)img + (size_t)pl * (HH * WW / 4);
    float4* d4 = (float4*)plane;
    #pragma unroll
    for (int it = 0; it < 8; ++it) d4[it * 512 + tid] = src[it * 512 + tid];
    __syncthreads();

    unsigned* dst = isE2 ? (P2 + (size_t)pl * PLANE_U32)
                         : ((pl < P1_SPLIT) ? (P1m + (size_t)pl * PLANE_U32)
                                            : (P1t + (size_t)(pl - P1_SPLIT) * PLANE_U32));
    for (int s = tid; s < 125 * 64; s += 512) {
        const int r = s >> 6;          // 0..124
        const int p = s & 63;          // u32 pair slot; cols 2p, 2p+1
        float v0 = 0.0f, v1 = 0.0f;
        const int j0 = 2 * p, j1 = 2 * p + 1;
        if (j0 < NPOL) {
            int pix = r * NPOL + j0;
            int pp = pk[pix]; float4 w = w4[pix];
            int xi0 = pp & 255, yi0 = (pp >> 8) & 255, xi1 = (pp >> 16) & 255, yi1 = (pp >> 24) & 255;
            v0 = w.x * plane[yi0 * WW + xi0] + w.y * plane[yi0 * WW + xi1]
               + w.z * plane[yi1 * WW + xi0] + w.w * plane[yi1 * WW + xi1];
        }
        if (j1 < NPOL) {
            int pix = r * NPOL + j1;
            int pp = pk[pix]; float4 w = w4[pix];
            int xi0 = pp & 255, yi0 = (pp >> 8) & 255, xi1 = (pp >> 16) & 255, yi1 = (pp >> 24) & 255;
            v1 = w.x * plane[yi0 * WW + xi0] + w.y * plane[yi0 * WW + xi1]
               + w.z * plane[yi1 * WW + xi0] + w.w * plane[yi1 * WW + xi1];
        }
        _Float16 h0 = (_Float16)v0; _Float16 l0 = (_Float16)(v0 - (float)h0);
        _Float16 h1 = (_Float16)v1; _Float16 l1 = (_Float16)(v1 - (float)h1);
        unsigned hw = (unsigned)__builtin_bit_cast(unsigned short, h0)
                    | ((unsigned)__builtin_bit_cast(unsigned short, h1) << 16);
        unsigned lw = (unsigned)__builtin_bit_cast(unsigned short, l0)
                    | ((unsigned)__builtin_bit_cast(unsigned short, l1) << 16);
        dst[r * 128 + p]      = hw;
        dst[r * 128 + 64 + p] = lw;
    }
}

// ---------------------------------------------------------------------------
// KZ: zero scores (4032 f32) + zero page (128 u32), contiguous.
// ---------------------------------------------------------------------------
__global__ __launch_bounds__(256) void kz_zero(float* __restrict__ p, int n) {
    int i = blockIdx.x * 256 + threadIdx.x;
    if (i < n) p[i] = 0.0f;
}

// ---------------------------------------------------------------------------
// K2: correlation as register-blocked MFMA GEMM. All fragment loads are single
// aligned dwordx4 (padded planes, zero-page row guards), zero unpack VALU.
// Grid 2048 = 512 q x 4 m; m folds {mt, flip} so the 4 partner blocks sharing
// one plane-set are 512 apart (= same XCD under round-robin). 2 channels/blk.
// Block 256 thr = 4 waves (2M x 2N), wave tile 64x64, 3-pass split-fp16.
// ---------------------------------------------------------------------------
__global__ __launch_bounds__(256, 3) void k2_gemm(const unsigned* __restrict__ P1m,
                                                  const unsigned* __restrict__ P1t,
                                                  const unsigned* __restrict__ P2,
                                                  const unsigned* __restrict__ zp,
                                                  float* __restrict__ scores) {
    __shared__ float sd[128];
    const int bid = blockIdx.x;          // 0..2047
    const int q  = bid & 511;            // 0..511
    const int m  = bid >> 9;             // 0..3
    const int mt = m & 1;
    const bool fl = (m & 2) != 0;
    const int bh  = q >> 5;              // 0..15
    const int kc0 = q & 31;              // 0..31
    const int b   = fl ? (BB - 1 - bh) : bh;
    const int kc  = fl ? (31 - kc0) : kc0;

    const int tid  = threadIdx.x;
    const int lane = tid & 63;
    const int wid  = tid >> 6;
    const int wm   = wid >> 1;            // 0..1
    const int wn   = wid & 1;             // 0..1
    const int frow = lane & 15;
    const int kq4  = (lane >> 4) << 2;    // k-group offset in u32 pairs: 0,4,8,12

    if (tid < 128) sd[tid] = 0.0f;

    f32x4 acc[4][4];
    #pragma unroll
    for (int mi = 0; mi < 4; ++mi)
        #pragma unroll
        for (int ni = 0; ni < 4; ++ni) acc[mi][ni] = (f32x4){0.f, 0.f, 0.f, 0.f};

    int rA[4], iB[4];
    #pragma unroll
    for (int x = 0; x < 4; ++x) {
        rA[x] = mt * 128 + wm * 64 + x * 16 + frow;   // aug row 0..255
        iB[x] = wn * 64 + x * 16 + frow;              // i 0..127
    }

    #pragma unroll
    for (int cl = 0; cl < 2; ++cl) {
        const int c   = kc * 2 + cl;
        const int plD = b * CC + c;
        const int plF = (BB - 1 - b) * CC + (CC - 1 - c);
        const unsigned* pD1 = (plD < P1_SPLIT) ? (P1m + (size_t)plD * PLANE_U32)
                                               : (P1t + (size_t)(plD - P1_SPLIT) * PLANE_U32);
        const unsigned* pF1 = (plF < P1_SPLIT) ? (P1m + (size_t)plF * PLANE_U32)
                                               : (P1t + (size_t)(plF - P1_SPLIT) * PLANE_U32);
        const unsigned* pD2 = P2 + (size_t)plD * PLANE_U32;

        const unsigned* rowA[4];
        const unsigned* rowB[4];
        #pragma unroll
        for (int x = 0; x < 4; ++x) {
            rowA[x] = (rA[x] < NPOL) ? (pD1 + rA[x] * 128 + kq4)
                    : ((rA[x] < 250) ? (pF1 + (rA[x] - NPOL) * 128 + kq4) : (zp + kq4));
            rowB[x] = (iB[x] < NPOL) ? (pD2 + iB[x] * 128 + kq4) : (zp + kq4);
        }

        #pragma unroll
        for (int jc = 0; jc < 4; ++jc) {
            const int off = jc * 16;     // 32 cols per jc chunk, 2 cols per u32
            U16 bhv[4], blv[4];
            #pragma unroll
            for (int ni = 0; ni < 4; ++ni) {
                bhv[ni].u = *(const uint4*)(rowB[ni] + off);
                blv[ni].u = *(const uint4*)(rowB[ni] + off + 64);
            }
            #pragma unroll
            for (int mi = 0; mi < 4; ++mi) {
                U16 ah, al;
                ah.u = *(const uint4*)(rowA[mi] + off);
                al.u = *(const uint4*)(rowA[mi] + off + 64);
                #pragma unroll
                for (int ni = 0; ni < 4; ++ni) {
                    acc[mi][ni] = __builtin_amdgcn_mfma_f32_16x16x32_f16(ah.v, bhv[ni].v, acc[mi][ni], 0, 0, 0);
                    acc[mi][ni] = __builtin_amdgcn_mfma_f32_16x16x32_f16(ah.v, blv[ni].v, acc[mi][ni], 0, 0, 0);
                    acc[mi][ni] = __builtin_amdgcn_mfma_f32_16x16x32_f16(al.v, bhv[ni].v, acc[mi][ni], 0, 0, 0);
                }
            }
        }
    }

    // Per-thread partial reduce over equal t = r - i (d = mi - ni), then LDS.
    float part[7][4];
    #pragma unroll
    for (int d = 0; d < 7; ++d)
        #pragma unroll
        for (int r = 0; r < 4; ++r) part[d][r] = 0.0f;
    #pragma unroll
    for (int mi = 0; mi < 4; ++mi)
        #pragma unroll
        for (int ni = 0; ni < 4; ++ni) {
            const int d = mi - ni + 3;
            #pragma unroll
            for (int r = 0; r < 4; ++r) part[d][r] += acc[mi][ni][r];
        }

    __syncthreads();   // sd zeros visible
    const int rB0 = mt * 128 + wm * 64 + ((lane >> 4) << 2);
    const int iB0 = wn * 64 + frow;
    #pragma unroll
    for (int d = 0; d < 7; ++d)
        #pragma unroll
        for (int r = 0; r < 4; ++r) {
            int t = rB0 - iB0 + (d - 3) * 16 + r;
            if (t >= 0 && t < NANG) atomicAdd(&sd[t], part[d][r]);
        }
    __syncthreads();
    if (tid < NANG) atomicAdd(&scores[b * NANG + tid], sd[tid]);
}

// ---------------------------------------------------------------------------
// K3: softmax over t, theta -> Mat. One block per b.
// ---------------------------------------------------------------------------
__global__ __launch_bounds__(128) void k3_theta(const float* __restrict__ scores, float* __restrict__ matOut) {
    const int b = blockIdx.x;
    const int t = threadIdx.x;   // 0..127
    __shared__ float sd[128];
    __shared__ float red[128];

    float sval = (t < NANG) ? scores[b * NANG + t] : -1e30f;
    sd[t]  = sval;
    red[t] = sval;
    __syncthreads();
    for (int st = 64; st > 0; st >>= 1) {
        if (t < st) red[t] = fmaxf(red[t], red[t + st]);
        __syncthreads();
    }
    const float m = red[0];
    __syncthreads();
    const float e = (t < NANG) ? expf(sd[t] - m) : 0.0f;
    red[t] = e;
    __syncthreads();
    for (int st = 64; st > 0; st >>= 1) {
        if (t < st) red[t] += red[t + st];
        __syncthreads();
    }
    const float Z = red[0];
    __syncthreads();
    const float ang = -PI_F + (float)t * (2.0f * PI_F / 125.0f);
    red[t] = e * ang;
    __syncthreads();
    for (int st = 64; st > 0; st >>= 1) {
        if (t < st) red[t] += red[t + st];
        __syncthreads();
    }
    if (t == 0) {
        float theta = red[0] / Z - PI_F;
        float cth = cosf(theta), sth = sinf(theta);
        float* M = matOut + b * 6;
        M[0] = cth; M[1] = -sth; M[2] = 0.0f;
        M[3] = sth; M[4] = cth;  M[5] = 0.0f;
    }
}

// ---------------------------------------------------------------------------
// K4: affine grid + grid_sample of Embd1. One block per (b,c) plane.
// ---------------------------------------------------------------------------
__global__ __launch_bounds__(512) void k4_affine(const float* __restrict__ img, const float* __restrict__ mat,
                                                 float* __restrict__ out) {
    __shared__ float plane[HH * WW];
    const int bc  = blockIdx.x;
    const int b   = bc >> 6;
    const int tid = threadIdx.x;
    const float4* src = (const float4*)img + (size_t)bc * (HH * WW / 4);
    float4* d4 = (float4*)plane;
    #pragma unroll
    for (int it = 0; it < 8; ++it) d4[it * 512 + tid] = src[it * 512 + tid];
    __syncthreads();
    const float M0 = mat[b * 6 + 0], M1 = mat[b * 6 + 1];
    const float M3 = mat[b * 6 + 3], M4 = mat[b * 6 + 4];
    const int base = bc * PIX;
    for (int pix = tid; pix < PIX; pix += 512) {
        int i = pix / NPOL;
        int j = pix - i * NPOL;
        float xx = -1.0f + (float)j * (2.0f / 124.0f);
        float yy = -1.0f + (float)i * (2.0f / 124.0f);
        float gx = M0 * xx + M1 * yy;
        float gy = M3 * xx + M4 * yy;
        float ix = (gx + 1.0f) * 0.5f * (float)(WW - 1);
        float iy = (gy + 1.0f) * 0.5f * (float)(HH - 1);
        float x0 = floorf(ix), y0 = floorf(iy);
        float x1 = x0 + 1.0f,  y1 = y0 + 1.0f;
        float wx0 = x1 - ix, wx1 = ix - x0;
        float wy0 = y1 - iy, wy1 = iy - y0;
        bool vx0 = (x0 >= 0.0f) && (x0 <= 127.0f);
        bool vx1 = (x1 >= 0.0f) && (x1 <= 127.0f);
        bool vy0 = (y0 >= 0.0f) && (y0 <= 127.0f);
        bool vy1 = (y1 >= 0.0f) && (y1 <= 127.0f);
        int xi0 = (int)fminf(fmaxf(x0, 0.0f), 127.0f);
        int xi1 = (int)fminf(fmaxf(x1, 0.0f), 127.0f);
        int yi0 = (int)fminf(fmaxf(y0, 0.0f), 127.0f);
        int yi1 = (int)fminf(fmaxf(y1, 0.0f), 127.0f);
        float val = (wx0 * wy0 * (float)(vx0 && vy0)) * plane[yi0 * WW + xi0]
                  + (wx1 * wy0 * (float)(vx1 && vy0)) * plane[yi0 * WW + xi1]
                  + (wx0 * wy1 * (float)(vx0 && vy1)) * plane[yi1 * WW + xi0]
                  + (wx1 * wy1 * (float)(vx1 && vy1)) * plane[yi1 * WW + xi1];
        out[base + pix] = val;
    }
}

// ---------------------------------------------------------------------------
// Layout.
// d_out: P1pad planes 0..1999 (128,000,000 B) | Mat at float idx 32,000,000.
// ws: P2pad 2048 planes (131,072,000) | P1 tail 48 planes (3,072,000) |
//     scores 4032 f32 | zeropage 128 u32 | pk 250,000 | w4 250,000.
// ---------------------------------------------------------------------------
#define OFF_P1T 131072000
#define OFF_SC  134144000
#define OFF_ZP  134160128
#define OFF_PK  134160640
#define OFF_W4  134410640

extern "C" void kernel_launch(void* const* d_in, const int* in_sizes, int n_in,
                              void* d_out, int out_size, void* d_ws, size_t ws_size,
                              hipStream_t stream) {
    const float* E1 = (const float*)d_in[0];
    const float* E2 = (const float*)d_in[1];
    float*    out    = (float*)d_out;
    unsigned* P1m    = (unsigned*)d_out;           // planes 0..1999
    float*    matOut = out + 32000000;             // 192 floats

    char*     ws     = (char*)d_ws;
    unsigned* P2pd   = (unsigned*)ws;
    unsigned* P1t    = (unsigned*)(ws + OFF_P1T);
    float*    scores = (float*)(ws + OFF_SC);
    unsigned* zp     = (unsigned*)(ws + OFF_ZP);
    int*      pk     = (int*)(ws + OFF_PK);
    float4*   w4     = (float4*)(ws + OFF_W4);

    k0_meta<<<(PIX + 255) / 256, 256, 0, stream>>>(pk, w4);
    kz_zero<<<(4160 + 255) / 256, 256, 0, stream>>>(scores, 4160);  // scores + zero page

    k1_sample<<<4096, 512, 0, stream>>>(E1, E2, P1m, P1t, P2pd, pk, w4);

    k2_gemm<<<2048, 256, 0, stream>>>(P1m, P1t, P2pd, zp, scores);
    k3_theta<<<BB, 128, 0, stream>>>(scores, matOut);
    k4_affine<<<BB * CC, 512, 0, stream>>>(E1, matOut, out);
}